// Round 1
// baseline (761.849 us; speedup 1.0000x reference)
//
#include <hip/hip_runtime.h>

// Problem constants
#define TOKENS 8192     // B*S
#define Dm 1024
#define Em 8
#define Hm 2048
#define Sm 2048
#define D2 512
#define SLOTS 16384     // TOKENS * K
#define SLOTPAD 16896   // SLOTS + 8*64 (worst-case per-expert padding)
#define BM 64
#define BN 64
#define KB 32

// Workspace layout (bytes)
#define OF_TAB 0ull                                   // float2[Sm*D2]      = 8 MB
#define OF_HID (OF_TAB + (size_t)Sm*D2*8)             // ushort[TOKENS*Dm]  = 16 MB
#define OF_ACT (OF_HID + (size_t)TOKENS*Dm*2)         // ushort[SLOTPAD*Hm] = 66 MB
#define OF_T2I (OF_ACT + (size_t)SLOTPAD*Hm*2)        // int[TOKENS*2]
#define OF_T2G (OF_T2I + (size_t)TOKENS*2*4)          // float[TOKENS*2]
#define OF_ST  (OF_T2G + (size_t)TOKENS*2*4)          // int[SLOTPAD]
#define OF_SG  (OF_ST + (size_t)SLOTPAD*4)            // float[SLOTPAD]
#define OF_MT  (OF_SG + (size_t)SLOTPAD*4)            // int meta[32]: counts[0..7], poff[8..16], cursor[17..24]

typedef __bf16 bf16x8 __attribute__((ext_vector_type(8)));
typedef short  s16x8  __attribute__((ext_vector_type(8)));
typedef float  f32x4  __attribute__((ext_vector_type(4)));

__device__ __forceinline__ unsigned short f2bf(float f) {
    union { float f; unsigned u; } v; v.f = f;
    unsigned r = v.u + 0x7fffu + ((v.u >> 16) & 1u);   // RNE
    return (unsigned short)(r >> 16);
}

__device__ __forceinline__ f32x4 mfma16(s16x8 a, s16x8 b, f32x4 c) {
    return __builtin_amdgcn_mfma_f32_16x16x32_bf16(
        __builtin_bit_cast(bf16x8, a), __builtin_bit_cast(bf16x8, b), c, 0, 0, 0);
}

// ---------------- init: slot sentinel + expert counts ----------------
__global__ void k_init(int* slot_token, int* meta) {
    int i = blockIdx.x * 256 + threadIdx.x;
    if (i < SLOTPAD) slot_token[i] = -1;
    if (i < 8) meta[i] = 0;
}

// ---------------- RoPE table ----------------
__global__ void k_table(float2* tab) {
    int i = blockIdx.x * 256 + threadIdx.x;   // < Sm*D2
    int s = i >> 9, j = i & 511;
    float inv = expf(-(float)j * (9.210340371976184f / 512.0f)); // 10000^(-j/512)
    float ang = (float)s * inv;
    tab[i] = make_float2(cosf(ang), sinf(ang));
}

// ---------------- per-token: rmsnorm + rope + router + residual ----------------
__global__ __launch_bounds__(256) void k_token(
    const float* __restrict__ x, const float* __restrict__ nw,
    const float* __restrict__ rW, const float2* __restrict__ tab,
    unsigned short* __restrict__ hid, float* __restrict__ out,
    int* __restrict__ t2i, float* __restrict__ t2g, int* __restrict__ meta)
{
    int t = blockIdx.x;
    int tid = threadIdx.x;
    int lane = tid & 63, wid = tid >> 6;
    int s = t & (Sm - 1);
    const float* xr = x + (size_t)t * Dm;

    float v0 = xr[tid], v1 = xr[tid + 256], v2 = xr[tid + 512], v3 = xr[tid + 768];
    float ss = v0*v0 + v1*v1 + v2*v2 + v3*v3;
    #pragma unroll
    for (int o = 32; o; o >>= 1) ss += __shfl_down(ss, o);
    __shared__ float red[4];
    if (lane == 0) red[wid] = ss;
    __syncthreads();
    float tot = red[0] + red[1] + red[2] + red[3];
    float rms = rsqrtf(tot * (1.0f / Dm) + 1e-6f);

    float n0 = v0 * rms * nw[tid];
    float n1 = v1 * rms * nw[tid + 256];
    float n2 = v2 * rms * nw[tid + 512];
    float n3 = v3 * rms * nw[tid + 768];

    float2 c0 = tab[s * D2 + tid];
    float2 c1 = tab[s * D2 + tid + 256];
    float h0 = n0 * c0.x - n2 * c0.y;
    float h2 = n0 * c0.y + n2 * c0.x;
    float h1 = n1 * c1.x - n3 * c1.y;
    float h3 = n1 * c1.y + n3 * c1.x;

    size_t base = (size_t)t * Dm;
    hid[base + tid]       = f2bf(h0);
    hid[base + tid + 256] = f2bf(h1);
    hid[base + tid + 512] = f2bf(h2);
    hid[base + tid + 768] = f2bf(h3);
    out[base + tid]       = v0;   // residual
    out[base + tid + 256] = v1;
    out[base + tid + 512] = v2;
    out[base + tid + 768] = v3;

    // router logits (fp32 hidden, pre-bf16)
    float p[8];
    #pragma unroll
    for (int e = 0; e < 8; e++) {
        const float* r = rW + (size_t)e * Dm;
        p[e] = h0 * r[tid] + h1 * r[tid + 256] + h2 * r[tid + 512] + h3 * r[tid + 768];
    }
    #pragma unroll
    for (int e = 0; e < 8; e++)
        #pragma unroll
        for (int o = 32; o; o >>= 1) p[e] += __shfl_down(p[e], o);
    __shared__ float rl[4][8];
    if (lane == 0) {
        #pragma unroll
        for (int e = 0; e < 8; e++) rl[wid][e] = p[e];
    }
    __syncthreads();
    if (tid == 0) {
        float lg[8];
        #pragma unroll
        for (int e = 0; e < 8; e++) lg[e] = rl[0][e] + rl[1][e] + rl[2][e] + rl[3][e];
        float m = lg[0];
        #pragma unroll
        for (int e = 1; e < 8; e++) m = fmaxf(m, lg[e]);
        int i0 = 0; float b0 = lg[0];
        #pragma unroll
        for (int e = 1; e < 8; e++) if (lg[e] > b0) { b0 = lg[e]; i0 = e; }
        int i1 = -1; float b1 = -3.0e38f;
        #pragma unroll
        for (int e = 0; e < 8; e++) if (e != i0 && lg[e] > b1) { b1 = lg[e]; i1 = e; }
        float p0 = expf(b0 - m), p1 = expf(b1 - m);
        float inv = 1.0f / (p0 + p1);
        t2i[2 * t] = i0; t2i[2 * t + 1] = i1;
        t2g[2 * t] = p0 * inv; t2g[2 * t + 1] = p1 * inv;
        atomicAdd(&meta[i0], 1);
        atomicAdd(&meta[i1], 1);
    }
}

// ---------------- prefix offsets (padded to BM) ----------------
__global__ void k_offsets(int* meta) {
    if (threadIdx.x == 0 && blockIdx.x == 0) {
        int acc = 0;
        for (int e = 0; e < 8; e++) {
            meta[8 + e] = acc;
            acc += ((meta[e] + BM - 1) / BM) * BM;
        }
        meta[16] = acc;                       // padded_total
        for (int e = 0; e < 8; e++) meta[17 + e] = meta[8 + e]; // cursors
    }
}

// ---------------- slot placement ----------------
__global__ void k_place(const int* __restrict__ t2i, const float* __restrict__ t2g,
                        int* __restrict__ slot_token, float* __restrict__ slot_gate,
                        int* __restrict__ meta) {
    int t = blockIdx.x * 256 + threadIdx.x;
    if (t >= TOKENS) return;
    #pragma unroll
    for (int k = 0; k < 2; k++) {
        int e = t2i[2 * t + k];
        int pos = atomicAdd(&meta[17 + e], 1);
        slot_token[pos] = t;
        slot_gate[pos]  = t2g[2 * t + k];
    }
}

// ---------------- GEMM1: act = silu(hid@w1^T) * (hid@w3^T) ----------------
__global__ __launch_bounds__(256) void k_gemm1(
    const unsigned short* __restrict__ hid,
    const float* __restrict__ w1, const float* __restrict__ w3,
    const int* __restrict__ slot_token, unsigned short* __restrict__ act,
    const int* __restrict__ meta)
{
    int row0 = blockIdx.y * BM;
    if (row0 >= meta[16]) return;
    int e = 0;
    #pragma unroll
    for (int q = 1; q < 8; q++) if (row0 >= meta[8 + q]) e = q;
    int h0 = blockIdx.x * BN;

    __shared__ unsigned short As[BM][KB + 8];
    __shared__ unsigned short Bs1[BN][KB + 8];
    __shared__ unsigned short Bs3[BN][KB + 8];

    int tid = threadIdx.x, lane = tid & 63, w = tid >> 6;
    int wm = w >> 1, wn = w & 1;
    int trow = tid >> 2, tseg = tid & 3;
    int frow = lane & 15, fk = (lane >> 4) * 8;

    int token = slot_token[row0 + trow];
    bool avalid = token >= 0;
    const unsigned short* aptr = hid + (size_t)(avalid ? token : 0) * Dm + tseg * 8;
    const float* b1p = w1 + ((size_t)e * Hm + h0 + trow) * Dm + tseg * 8;
    const float* b3p = w3 + ((size_t)e * Hm + h0 + trow) * Dm + tseg * 8;

    f32x4 accG[2][2] = {};
    f32x4 accU[2][2] = {};

    for (int k0 = 0; k0 < Dm; k0 += KB) {
        s16x8 av = {0,0,0,0,0,0,0,0};
        if (avalid) av = *(const s16x8*)(aptr + k0);
        float4 ba = ((const float4*)(b1p + k0))[0];
        float4 bb = ((const float4*)(b1p + k0))[1];
        float4 ca = ((const float4*)(b3p + k0))[0];
        float4 cb = ((const float4*)(b3p + k0))[1];
        s16x8 bv, cv;
        bv[0]=(short)f2bf(ba.x); bv[1]=(short)f2bf(ba.y); bv[2]=(short)f2bf(ba.z); bv[3]=(short)f2bf(ba.w);
        bv[4]=(short)f2bf(bb.x); bv[5]=(short)f2bf(bb.y); bv[6]=(short)f2bf(bb.z); bv[7]=(short)f2bf(bb.w);
        cv[0]=(short)f2bf(ca.x); cv[1]=(short)f2bf(ca.y); cv[2]=(short)f2bf(ca.z); cv[3]=(short)f2bf(ca.w);
        cv[4]=(short)f2bf(cb.x); cv[5]=(short)f2bf(cb.y); cv[6]=(short)f2bf(cb.z); cv[7]=(short)f2bf(cb.w);

        *(s16x8*)&As[trow][tseg * 8]  = av;
        *(s16x8*)&Bs1[trow][tseg * 8] = bv;
        *(s16x8*)&Bs3[trow][tseg * 8] = cv;
        __syncthreads();

        s16x8 a0  = *(const s16x8*)&As[wm * 32 + frow][fk];
        s16x8 a1  = *(const s16x8*)&As[wm * 32 + 16 + frow][fk];
        s16x8 b10 = *(const s16x8*)&Bs1[wn * 32 + frow][fk];
        s16x8 b11 = *(const s16x8*)&Bs1[wn * 32 + 16 + frow][fk];
        s16x8 b30 = *(const s16x8*)&Bs3[wn * 32 + frow][fk];
        s16x8 b31 = *(const s16x8*)&Bs3[wn * 32 + 16 + frow][fk];

        accG[0][0] = mfma16(a0, b10, accG[0][0]);
        accG[0][1] = mfma16(a0, b11, accG[0][1]);
        accG[1][0] = mfma16(a1, b10, accG[1][0]);
        accG[1][1] = mfma16(a1, b11, accG[1][1]);
        accU[0][0] = mfma16(a0, b30, accU[0][0]);
        accU[0][1] = mfma16(a0, b31, accU[0][1]);
        accU[1][0] = mfma16(a1, b30, accU[1][0]);
        accU[1][1] = mfma16(a1, b31, accU[1][1]);
        __syncthreads();
    }

    #pragma unroll
    for (int m = 0; m < 2; m++)
        #pragma unroll
        for (int n = 0; n < 2; n++)
            #pragma unroll
            for (int r = 0; r < 4; r++) {
                int sr = row0 + wm * 32 + m * 16 + (lane >> 4) * 4 + r;
                int hc = h0 + wn * 32 + n * 16 + (lane & 15);
                float g = accG[m][n][r], u = accU[m][n][r];
                float a = g / (1.0f + expf(-g)) * u;
                act[(size_t)sr * Hm + hc] = f2bf(a);
            }
}

// ---------------- GEMM2: out[token] += gate * (act @ w2^T) ----------------
__global__ __launch_bounds__(256) void k_gemm2(
    const unsigned short* __restrict__ act, const float* __restrict__ w2,
    const int* __restrict__ slot_token, const float* __restrict__ slot_gate,
    float* __restrict__ out, const int* __restrict__ meta)
{
    int row0 = blockIdx.y * BM;
    if (row0 >= meta[16]) return;
    int e = 0;
    #pragma unroll
    for (int q = 1; q < 8; q++) if (row0 >= meta[8 + q]) e = q;
    int d0 = blockIdx.x * BN;

    __shared__ unsigned short As[BM][KB + 8];
    __shared__ unsigned short Bs[BN][KB + 8];
    __shared__ int   stok[BM];
    __shared__ float sgat[BM];

    int tid = threadIdx.x, lane = tid & 63, w = tid >> 6;
    int wm = w >> 1, wn = w & 1;
    int trow = tid >> 2, tseg = tid & 3;
    int frow = lane & 15, fk = (lane >> 4) * 8;

    if (tid < BM) { stok[tid] = slot_token[row0 + tid]; sgat[tid] = slot_gate[row0 + tid]; }

    const unsigned short* ap = act + (size_t)(row0 + trow) * Hm + tseg * 8;
    const float* bp = w2 + ((size_t)e * Dm + d0 + trow) * Hm + tseg * 8;

    f32x4 acc[2][2] = {};

    for (int k0 = 0; k0 < Hm; k0 += KB) {
        s16x8 av = *(const s16x8*)(ap + k0);
        float4 ba = ((const float4*)(bp + k0))[0];
        float4 bb = ((const float4*)(bp + k0))[1];
        s16x8 bv;
        bv[0]=(short)f2bf(ba.x); bv[1]=(short)f2bf(ba.y); bv[2]=(short)f2bf(ba.z); bv[3]=(short)f2bf(ba.w);
        bv[4]=(short)f2bf(bb.x); bv[5]=(short)f2bf(bb.y); bv[6]=(short)f2bf(bb.z); bv[7]=(short)f2bf(bb.w);

        *(s16x8*)&As[trow][tseg * 8] = av;
        *(s16x8*)&Bs[trow][tseg * 8] = bv;
        __syncthreads();

        s16x8 a0 = *(const s16x8*)&As[wm * 32 + frow][fk];
        s16x8 a1 = *(const s16x8*)&As[wm * 32 + 16 + frow][fk];
        s16x8 b0 = *(const s16x8*)&Bs[wn * 32 + frow][fk];
        s16x8 b1 = *(const s16x8*)&Bs[wn * 32 + 16 + frow][fk];

        acc[0][0] = mfma16(a0, b0, acc[0][0]);
        acc[0][1] = mfma16(a0, b1, acc[0][1]);
        acc[1][0] = mfma16(a1, b0, acc[1][0]);
        acc[1][1] = mfma16(a1, b1, acc[1][1]);
        __syncthreads();
    }

    #pragma unroll
    for (int m = 0; m < 2; m++)
        #pragma unroll
        for (int n = 0; n < 2; n++)
            #pragma unroll
            for (int r = 0; r < 4; r++) {
                int srl = wm * 32 + m * 16 + (lane >> 4) * 4 + r;
                int token = stok[srl];
                if (token >= 0) {
                    int dc = d0 + wn * 32 + n * 16 + (lane & 15);
                    atomicAdd(&out[(size_t)token * Dm + dc], sgat[srl] * acc[m][n][r]);
                }
            }
}

extern "C" void kernel_launch(void* const* d_in, const int* in_sizes, int n_in,
                              void* d_out, int out_size, void* d_ws, size_t ws_size,
                              hipStream_t stream) {
    const float* x  = (const float*)d_in[0];
    const float* nw = (const float*)d_in[1];
    const float* rW = (const float*)d_in[2];
    const float* w1 = (const float*)d_in[3];
    const float* w3 = (const float*)d_in[4];
    const float* w2 = (const float*)d_in[5];
    float* out = (float*)d_out;
    char* ws = (char*)d_ws;

    float2* tab = (float2*)(ws + OF_TAB);
    unsigned short* hid = (unsigned short*)(ws + OF_HID);
    unsigned short* act = (unsigned short*)(ws + OF_ACT);
    int*   t2i  = (int*)(ws + OF_T2I);
    float* t2g  = (float*)(ws + OF_T2G);
    int*   stok = (int*)(ws + OF_ST);
    float* sgat = (float*)(ws + OF_SG);
    int*   meta = (int*)(ws + OF_MT);

    k_init<<<(SLOTPAD + 255) / 256, 256, 0, stream>>>(stok, meta);
    k_table<<<(Sm * D2) / 256, 256, 0, stream>>>(tab);
    k_token<<<TOKENS, 256, 0, stream>>>(x, nw, rW, tab, hid, out, t2i, t2g, meta);
    k_offsets<<<1, 64, 0, stream>>>(meta);
    k_place<<<TOKENS / 256, 256, 0, stream>>>(t2i, t2g, stok, sgat, meta);

    dim3 g1(Hm / BN, SLOTPAD / BM);
    k_gemm1<<<g1, 256, 0, stream>>>(hid, w1, w3, stok, act, meta);
    dim3 g2(Dm / BN, SLOTPAD / BM);
    k_gemm2<<<g2, 256, 0, stream>>>(act, w2, stok, sgat, out, meta);
}

// Round 2
// 648.757 us; speedup vs baseline: 1.1743x; 1.1743x over previous
//
#include <hip/hip_runtime.h>

// Problem constants
#define TOKENS 8192     // B*S
#define Dm 1024
#define Hm 2048
#define Sm 2048
#define D2 512
#define SLOTS 16384     // TOKENS * K
#define PADU 128        // expert segment padding unit (= GEMM row-tile)
#define SLOTPAD (SLOTS + 8*PADU)   // 17408
#define NWE 16777216    // weight elements per array (8*2048*1024)

// Workspace layout (bytes)
#define OF_TAB 0ull                                   // float2[Sm*D2]       8 MB
#define OF_HID (OF_TAB + (size_t)Sm*D2*8)             // ushort[TOKENS*Dm]  16.8 MB
#define OF_ACT (OF_HID + (size_t)TOKENS*Dm*2)         // ushort[SLOTPAD*Hm] 71.3 MB
#define OF_W1B (OF_ACT + (size_t)SLOTPAD*Hm*2)        // ushort[NWE]        33.6 MB
#define OF_W3B (OF_W1B + (size_t)NWE*2)               // ushort[NWE]        33.6 MB
#define OF_W2B (OF_W3B + (size_t)NWE*2)               // ushort[NWE]        33.6 MB
#define OF_T2I (OF_W2B + (size_t)NWE*2)               // int[TOKENS*2]
#define OF_T2G (OF_T2I + (size_t)TOKENS*2*4)          // float[TOKENS*2]
#define OF_ST  (OF_T2G + (size_t)TOKENS*2*4)          // int[SLOTPAD]
#define OF_SG  (OF_ST + (size_t)SLOTPAD*4)            // float[SLOTPAD]
#define OF_MT  (OF_SG + (size_t)SLOTPAD*4)            // int meta[32]

typedef __bf16 bf16x8 __attribute__((ext_vector_type(8)));
typedef short  s16x8  __attribute__((ext_vector_type(8)));
typedef float  f32x4  __attribute__((ext_vector_type(4)));

__device__ __forceinline__ unsigned short f2bf(float f) {
    union { float f; unsigned u; } v; v.f = f;
    unsigned r = v.u + 0x7fffu + ((v.u >> 16) & 1u);   // RNE
    return (unsigned short)(r >> 16);
}

__device__ __forceinline__ f32x4 mfma16(s16x8 a, s16x8 b, f32x4 c) {
    return __builtin_amdgcn_mfma_f32_16x16x32_bf16(
        __builtin_bit_cast(bf16x8, a), __builtin_bit_cast(bf16x8, b), c, 0, 0, 0);
}

// async global->LDS, 16 bytes per lane
__device__ __forceinline__ void gld16(const void* g, void* l) {
    __builtin_amdgcn_global_load_lds(
        (const __attribute__((address_space(1))) void*)g,
        (__attribute__((address_space(3))) void*)l, 16, 0, 0);
}

// ---------------- init ----------------
__global__ void k_init(int* slot_token, int* meta) {
    int i = blockIdx.x * 256 + threadIdx.x;
    if (i < SLOTPAD) slot_token[i] = -1;
    if (i < 8) meta[i] = 0;
}

// ---------------- fp32 -> bf16 weight conversion ----------------
__global__ __launch_bounds__(256) void k_convert(const float* __restrict__ s,
                                                 unsigned short* __restrict__ d) {
    size_t i = ((size_t)blockIdx.x * 256 + threadIdx.x) * 8;
    float4 a = *(const float4*)(s + i);
    float4 b = *(const float4*)(s + i + 4);
    s16x8 v;
    v[0]=(short)f2bf(a.x); v[1]=(short)f2bf(a.y); v[2]=(short)f2bf(a.z); v[3]=(short)f2bf(a.w);
    v[4]=(short)f2bf(b.x); v[5]=(short)f2bf(b.y); v[6]=(short)f2bf(b.z); v[7]=(short)f2bf(b.w);
    *(s16x8*)(d + i) = v;
}

// ---------------- RoPE table ----------------
__global__ void k_table(float2* tab) {
    int i = blockIdx.x * 256 + threadIdx.x;   // < Sm*D2
    int s = i >> 9, j = i & 511;
    float inv = expf(-(float)j * (9.210340371976184f / 512.0f)); // 10000^(-j/512)
    float ang = (float)s * inv;
    tab[i] = make_float2(cosf(ang), sinf(ang));
}

// ---------------- per-token: rmsnorm + rope + router + residual ----------------
__global__ __launch_bounds__(256) void k_token(
    const float* __restrict__ x, const float* __restrict__ nw,
    const float* __restrict__ rW, const float2* __restrict__ tab,
    unsigned short* __restrict__ hid, float* __restrict__ out,
    int* __restrict__ t2i, float* __restrict__ t2g, int* __restrict__ meta)
{
    int t = blockIdx.x;
    int tid = threadIdx.x;
    int lane = tid & 63, wid = tid >> 6;
    int s = t & (Sm - 1);
    const float* xr = x + (size_t)t * Dm;

    float v0 = xr[tid], v1 = xr[tid + 256], v2 = xr[tid + 512], v3 = xr[tid + 768];
    float ss = v0*v0 + v1*v1 + v2*v2 + v3*v3;
    #pragma unroll
    for (int o = 32; o; o >>= 1) ss += __shfl_down(ss, o);
    __shared__ float red[4];
    if (lane == 0) red[wid] = ss;
    __syncthreads();
    float tot = red[0] + red[1] + red[2] + red[3];
    float rms = rsqrtf(tot * (1.0f / Dm) + 1e-6f);

    float n0 = v0 * rms * nw[tid];
    float n1 = v1 * rms * nw[tid + 256];
    float n2 = v2 * rms * nw[tid + 512];
    float n3 = v3 * rms * nw[tid + 768];

    float2 c0 = tab[s * D2 + tid];
    float2 c1 = tab[s * D2 + tid + 256];
    float h0 = n0 * c0.x - n2 * c0.y;
    float h2 = n0 * c0.y + n2 * c0.x;
    float h1 = n1 * c1.x - n3 * c1.y;
    float h3 = n1 * c1.y + n3 * c1.x;

    size_t base = (size_t)t * Dm;
    hid[base + tid]       = f2bf(h0);
    hid[base + tid + 256] = f2bf(h1);
    hid[base + tid + 512] = f2bf(h2);
    hid[base + tid + 768] = f2bf(h3);
    out[base + tid]       = v0;   // residual
    out[base + tid + 256] = v1;
    out[base + tid + 512] = v2;
    out[base + tid + 768] = v3;

    float p[8];
    #pragma unroll
    for (int e = 0; e < 8; e++) {
        const float* r = rW + (size_t)e * Dm;
        p[e] = h0 * r[tid] + h1 * r[tid + 256] + h2 * r[tid + 512] + h3 * r[tid + 768];
    }
    #pragma unroll
    for (int e = 0; e < 8; e++)
        #pragma unroll
        for (int o = 32; o; o >>= 1) p[e] += __shfl_down(p[e], o);
    __shared__ float rl[4][8];
    if (lane == 0) {
        #pragma unroll
        for (int e = 0; e < 8; e++) rl[wid][e] = p[e];
    }
    __syncthreads();
    if (tid == 0) {
        float lg[8];
        #pragma unroll
        for (int e = 0; e < 8; e++) lg[e] = rl[0][e] + rl[1][e] + rl[2][e] + rl[3][e];
        float m = lg[0];
        #pragma unroll
        for (int e = 1; e < 8; e++) m = fmaxf(m, lg[e]);
        int i0 = 0; float b0 = lg[0];
        #pragma unroll
        for (int e = 1; e < 8; e++) if (lg[e] > b0) { b0 = lg[e]; i0 = e; }
        int i1 = -1; float b1 = -3.0e38f;
        #pragma unroll
        for (int e = 0; e < 8; e++) if (e != i0 && lg[e] > b1) { b1 = lg[e]; i1 = e; }
        float p0 = expf(b0 - m), p1 = expf(b1 - m);
        float inv = 1.0f / (p0 + p1);
        t2i[2 * t] = i0; t2i[2 * t + 1] = i1;
        t2g[2 * t] = p0 * inv; t2g[2 * t + 1] = p1 * inv;
        atomicAdd(&meta[i0], 1);
        atomicAdd(&meta[i1], 1);
    }
}

// ---------------- prefix offsets (padded to PADU=128) ----------------
__global__ void k_offsets(int* meta) {
    if (threadIdx.x == 0 && blockIdx.x == 0) {
        int acc = 0;
        for (int e = 0; e < 8; e++) {
            meta[8 + e] = acc;
            acc += ((meta[e] + PADU - 1) / PADU) * PADU;
        }
        meta[16] = acc;                       // padded_total
        for (int e = 0; e < 8; e++) meta[17 + e] = meta[8 + e]; // cursors
    }
}

// ---------------- slot placement ----------------
__global__ void k_place(const int* __restrict__ t2i, const float* __restrict__ t2g,
                        int* __restrict__ slot_token, float* __restrict__ slot_gate,
                        int* __restrict__ meta) {
    int t = blockIdx.x * 256 + threadIdx.x;
    if (t >= TOKENS) return;
    #pragma unroll
    for (int k = 0; k < 2; k++) {
        int e = t2i[2 * t + k];
        int pos = atomicAdd(&meta[17 + e], 1);
        slot_token[pos] = t;
        slot_gate[pos]  = t2g[2 * t + k];
    }
}

// ---------------- GEMM1: act = silu(hid@w1^T) * (hid@w3^T) ----------------
// 128 rows x 64 H-cols per block; dual-B (w1 rows 0-63 of Bs, w3 rows 64-127)
__global__ __launch_bounds__(256) void k_gemm1(
    const unsigned short* __restrict__ hid,
    const unsigned short* __restrict__ w1b, const unsigned short* __restrict__ w3b,
    const int* __restrict__ slot_token, unsigned short* __restrict__ act,
    const int* __restrict__ meta)
{
    int row0 = blockIdx.y * 128;
    if (row0 >= meta[16]) return;
    int e = 0;
    #pragma unroll
    for (int q = 1; q < 8; q++) if (row0 >= meta[8 + q]) e = q;
    int h0 = blockIdx.x * 64;

    __shared__ unsigned short As[128 * 32];
    __shared__ unsigned short Bs[128 * 32];

    int tid = threadIdx.x, lane = tid & 63, w = tid >> 6;
    int wm = w >> 1, wn = w & 1;
    int frow = lane & 15, fk = (lane >> 4) * 8;
    int srow = tid >> 2, seg = tid & 3;     // staging: row 0..63, 8-elem segment

    int tA0 = slot_token[row0 + srow];       if (tA0 < 0) tA0 = 0;
    int tA1 = slot_token[row0 + 64 + srow];  if (tA1 < 0) tA1 = 0;
    const unsigned short* srcA0 = hid + (size_t)tA0 * Dm + seg * 8;
    const unsigned short* srcA1 = hid + (size_t)tA1 * Dm + seg * 8;
    const unsigned short* srcB1 = w1b + ((size_t)e * Hm + h0 + srow) * Dm + seg * 8;
    const unsigned short* srcB3 = w3b + ((size_t)e * Hm + h0 + srow) * Dm + seg * 8;
    unsigned short* ldsA0 = &As[tid * 8];
    unsigned short* ldsA1 = &As[2048 + tid * 8];
    unsigned short* ldsB1 = &Bs[tid * 8];
    unsigned short* ldsB3 = &Bs[2048 + tid * 8];

    f32x4 accG[4][2] = {};
    f32x4 accU[4][2] = {};

    for (int k0 = 0; k0 < Dm; k0 += 32) {
        gld16(srcA0 + k0, ldsA0);
        gld16(srcA1 + k0, ldsA1);
        gld16(srcB1 + k0, ldsB1);
        gld16(srcB3 + k0, ldsB3);
        __syncthreads();

        s16x8 am[4], bg[2], bu[2];
        #pragma unroll
        for (int i = 0; i < 4; i++)
            am[i] = *(const s16x8*)&As[(wm * 64 + i * 16 + frow) * 32 + fk];
        #pragma unroll
        for (int j = 0; j < 2; j++) {
            bg[j] = *(const s16x8*)&Bs[(wn * 32 + j * 16 + frow) * 32 + fk];
            bu[j] = *(const s16x8*)&Bs[(64 + wn * 32 + j * 16 + frow) * 32 + fk];
        }
        #pragma unroll
        for (int i = 0; i < 4; i++)
            #pragma unroll
            for (int j = 0; j < 2; j++) {
                accG[i][j] = mfma16(am[i], bg[j], accG[i][j]);
                accU[i][j] = mfma16(am[i], bu[j], accU[i][j]);
            }
        __syncthreads();
    }

    #pragma unroll
    for (int i = 0; i < 4; i++)
        #pragma unroll
        for (int j = 0; j < 2; j++)
            #pragma unroll
            for (int r = 0; r < 4; r++) {
                int sr = row0 + wm * 64 + i * 16 + (lane >> 4) * 4 + r;
                int hc = h0 + wn * 32 + j * 16 + (lane & 15);
                float g = accG[i][j][r], u = accU[i][j][r];
                float a = g / (1.0f + expf(-g)) * u;
                act[(size_t)sr * Hm + hc] = f2bf(a);
            }
}

// ---------------- GEMM2: out[token] += gate * (act @ w2^T) ----------------
// 128 rows x 128 D-cols per block
__global__ __launch_bounds__(256) void k_gemm2(
    const unsigned short* __restrict__ act, const unsigned short* __restrict__ w2b,
    const int* __restrict__ slot_token, const float* __restrict__ slot_gate,
    float* __restrict__ out, const int* __restrict__ meta)
{
    int row0 = blockIdx.y * 128;
    if (row0 >= meta[16]) return;
    int e = 0;
    #pragma unroll
    for (int q = 1; q < 8; q++) if (row0 >= meta[8 + q]) e = q;
    int d0 = blockIdx.x * 128;

    __shared__ unsigned short As[128 * 32];
    __shared__ unsigned short Bs[128 * 32];
    __shared__ int   stok[128];
    __shared__ float sgat[128];

    int tid = threadIdx.x, lane = tid & 63, w = tid >> 6;
    int wm = w >> 1, wn = w & 1;
    int frow = lane & 15, fk = (lane >> 4) * 8;
    int srow = tid >> 2, seg = tid & 3;

    if (tid < 128) { stok[tid] = slot_token[row0 + tid]; sgat[tid] = slot_gate[row0 + tid]; }

    const unsigned short* srcA0 = act + (size_t)(row0 + srow) * Hm + seg * 8;
    const unsigned short* srcA1 = act + (size_t)(row0 + 64 + srow) * Hm + seg * 8;
    const unsigned short* srcB0 = w2b + ((size_t)e * Dm + d0 + srow) * Hm + seg * 8;
    const unsigned short* srcB1 = w2b + ((size_t)e * Dm + d0 + 64 + srow) * Hm + seg * 8;
    unsigned short* ldsA0 = &As[tid * 8];
    unsigned short* ldsA1 = &As[2048 + tid * 8];
    unsigned short* ldsB0 = &Bs[tid * 8];
    unsigned short* ldsB1 = &Bs[2048 + tid * 8];

    f32x4 acc[4][4] = {};

    for (int k0 = 0; k0 < Hm; k0 += 32) {
        gld16(srcA0 + k0, ldsA0);
        gld16(srcA1 + k0, ldsA1);
        gld16(srcB0 + k0, ldsB0);
        gld16(srcB1 + k0, ldsB1);
        __syncthreads();

        s16x8 am[4], bn[4];
        #pragma unroll
        for (int i = 0; i < 4; i++)
            am[i] = *(const s16x8*)&As[(wm * 64 + i * 16 + frow) * 32 + fk];
        #pragma unroll
        for (int j = 0; j < 4; j++)
            bn[j] = *(const s16x8*)&Bs[(wn * 64 + j * 16 + frow) * 32 + fk];
        #pragma unroll
        for (int i = 0; i < 4; i++)
            #pragma unroll
            for (int j = 0; j < 4; j++)
                acc[i][j] = mfma16(am[i], bn[j], acc[i][j]);
        __syncthreads();
    }

    #pragma unroll
    for (int i = 0; i < 4; i++) {
        #pragma unroll
        for (int r = 0; r < 4; r++) {
            int srl = wm * 64 + i * 16 + (lane >> 4) * 4 + r;
            int token = stok[srl];
            if (token >= 0) {
                float gate = sgat[srl];
                #pragma unroll
                for (int j = 0; j < 4; j++) {
                    int dc = d0 + wn * 64 + j * 16 + (lane & 15);
                    atomicAdd(&out[(size_t)token * Dm + dc], gate * acc[i][j][r]);
                }
            }
        }
    }
}

extern "C" void kernel_launch(void* const* d_in, const int* in_sizes, int n_in,
                              void* d_out, int out_size, void* d_ws, size_t ws_size,
                              hipStream_t stream) {
    const float* x  = (const float*)d_in[0];
    const float* nw = (const float*)d_in[1];
    const float* rW = (const float*)d_in[2];
    const float* w1 = (const float*)d_in[3];
    const float* w3 = (const float*)d_in[4];
    const float* w2 = (const float*)d_in[5];
    float* out = (float*)d_out;
    char* ws = (char*)d_ws;

    float2* tab = (float2*)(ws + OF_TAB);
    unsigned short* hid = (unsigned short*)(ws + OF_HID);
    unsigned short* act = (unsigned short*)(ws + OF_ACT);
    unsigned short* w1b = (unsigned short*)(ws + OF_W1B);
    unsigned short* w3b = (unsigned short*)(ws + OF_W3B);
    unsigned short* w2b = (unsigned short*)(ws + OF_W2B);
    int*   t2i  = (int*)(ws + OF_T2I);
    float* t2g  = (float*)(ws + OF_T2G);
    int*   stok = (int*)(ws + OF_ST);
    float* sgat = (float*)(ws + OF_SG);
    int*   meta = (int*)(ws + OF_MT);

    k_init<<<(SLOTPAD + 255) / 256, 256, 0, stream>>>(stok, meta);
    k_table<<<(Sm * D2) / 256, 256, 0, stream>>>(tab);
    k_convert<<<NWE / (256 * 8), 256, 0, stream>>>(w1, w1b);
    k_convert<<<NWE / (256 * 8), 256, 0, stream>>>(w3, w3b);
    k_convert<<<NWE / (256 * 8), 256, 0, stream>>>(w2, w2b);
    k_token<<<TOKENS, 256, 0, stream>>>(x, nw, rW, tab, hid, out, t2i, t2g, meta);
    k_offsets<<<1, 64, 0, stream>>>(meta);
    k_place<<<TOKENS / 256, 256, 0, stream>>>(t2i, t2g, stok, sgat, meta);

    dim3 g1(Hm / 64, SLOTPAD / 128);
    k_gemm1<<<g1, 256, 0, stream>>>(hid, w1b, w3b, stok, act, meta);
    dim3 g2(Dm / 128, SLOTPAD / 128);
    k_gemm2<<<g2, 256, 0, stream>>>(act, w2b, stok, sgat, out, meta);
}

// Round 3
// 628.389 us; speedup vs baseline: 1.2124x; 1.0324x over previous
//
#include <hip/hip_runtime.h>

// Problem constants
#define TOKENS 8192     // B*S
#define Dm 1024
#define Hm 2048
#define Sm 2048
#define D2 512
#define SLOTS 16384     // TOKENS * K
#define PADU 128        // expert segment padding unit (= GEMM row-tile)
#define SLOTPAD (SLOTS + 8*PADU)   // 17408
#define NWE 16777216    // weight elements per array (8*2048*1024)

// Workspace layout (bytes)
#define OF_TAB 0ull                                   // float2[Sm*D2]       8 MB
#define OF_HID (OF_TAB + (size_t)Sm*D2*8)             // ushort[TOKENS*Dm]  16.8 MB
#define OF_ACT (OF_HID + (size_t)TOKENS*Dm*2)         // ushort[SLOTPAD*Hm] 71.3 MB
#define OF_W1B (OF_ACT + (size_t)SLOTPAD*Hm*2)        // ushort[NWE]        33.6 MB
#define OF_W3B (OF_W1B + (size_t)NWE*2)               // ushort[NWE]        33.6 MB
#define OF_W2B (OF_W3B + (size_t)NWE*2)               // ushort[NWE]        33.6 MB
#define OF_T2I (OF_W2B + (size_t)NWE*2)               // int[TOKENS*2]
#define OF_T2G (OF_T2I + (size_t)TOKENS*2*4)          // float[TOKENS*2]
#define OF_T2S (OF_T2G + (size_t)TOKENS*2*4)          // int[TOKENS*2]
#define OF_ST  (OF_T2S + (size_t)TOKENS*2*4)          // int[SLOTPAD]
#define OF_SG  (OF_ST + (size_t)SLOTPAD*4)            // float[SLOTPAD]
#define OF_MT  (OF_SG + (size_t)SLOTPAD*4)            // int meta[32]
#define OF_SO  (OF_MT + 1024)                         // ushort sout[SLOTPAD*Dm] 35.7 MB

typedef __bf16 bf16x8 __attribute__((ext_vector_type(8)));
typedef short  s16x8  __attribute__((ext_vector_type(8)));
typedef float  f32x4  __attribute__((ext_vector_type(4)));

__device__ __forceinline__ unsigned short f2bf(float f) {
    union { float f; unsigned u; } v; v.f = f;
    unsigned r = v.u + 0x7fffu + ((v.u >> 16) & 1u);   // RNE
    return (unsigned short)(r >> 16);
}

__device__ __forceinline__ float bf2f(unsigned short u) {
    union { unsigned u; float f; } v; v.u = ((unsigned)u) << 16;
    return v.f;
}

__device__ __forceinline__ f32x4 mfma16(s16x8 a, s16x8 b, f32x4 c) {
    return __builtin_amdgcn_mfma_f32_16x16x32_bf16(
        __builtin_bit_cast(bf16x8, a), __builtin_bit_cast(bf16x8, b), c, 0, 0, 0);
}

// async global->LDS, 16 bytes per lane
__device__ __forceinline__ void gld16(const void* g, void* l) {
    __builtin_amdgcn_global_load_lds(
        (const __attribute__((address_space(1))) void*)g,
        (__attribute__((address_space(3))) void*)l, 16, 0, 0);
}

// ---------------- init ----------------
__global__ void k_init(int* slot_token, int* meta) {
    int i = blockIdx.x * 256 + threadIdx.x;
    if (i < SLOTPAD) slot_token[i] = -1;
    if (i < 8) meta[i] = 0;
}

// ---------------- fp32 -> bf16 weight conversion ----------------
__global__ __launch_bounds__(256) void k_convert(const float* __restrict__ s,
                                                 unsigned short* __restrict__ d) {
    size_t i = ((size_t)blockIdx.x * 256 + threadIdx.x) * 8;
    float4 a = *(const float4*)(s + i);
    float4 b = *(const float4*)(s + i + 4);
    s16x8 v;
    v[0]=(short)f2bf(a.x); v[1]=(short)f2bf(a.y); v[2]=(short)f2bf(a.z); v[3]=(short)f2bf(a.w);
    v[4]=(short)f2bf(b.x); v[5]=(short)f2bf(b.y); v[6]=(short)f2bf(b.z); v[7]=(short)f2bf(b.w);
    *(s16x8*)(d + i) = v;
}

// ---------------- RoPE table ----------------
__global__ void k_table(float2* tab) {
    int i = blockIdx.x * 256 + threadIdx.x;   // < Sm*D2
    int s = i >> 9, j = i & 511;
    float inv = expf(-(float)j * (9.210340371976184f / 512.0f)); // 10000^(-j/512)
    float ang = (float)s * inv;
    tab[i] = make_float2(cosf(ang), sinf(ang));
}

// ---------------- per-token: rmsnorm + rope + router ----------------
__global__ __launch_bounds__(256) void k_token(
    const float* __restrict__ x, const float* __restrict__ nw,
    const float* __restrict__ rW, const float2* __restrict__ tab,
    unsigned short* __restrict__ hid,
    int* __restrict__ t2i, float* __restrict__ t2g, int* __restrict__ meta)
{
    int t = blockIdx.x;
    int tid = threadIdx.x;
    int lane = tid & 63, wid = tid >> 6;
    int s = t & (Sm - 1);
    const float* xr = x + (size_t)t * Dm;

    float v0 = xr[tid], v1 = xr[tid + 256], v2 = xr[tid + 512], v3 = xr[tid + 768];
    float ss = v0*v0 + v1*v1 + v2*v2 + v3*v3;
    #pragma unroll
    for (int o = 32; o; o >>= 1) ss += __shfl_down(ss, o);
    __shared__ float red[4];
    if (lane == 0) red[wid] = ss;
    __syncthreads();
    float tot = red[0] + red[1] + red[2] + red[3];
    float rms = rsqrtf(tot * (1.0f / Dm) + 1e-6f);

    float n0 = v0 * rms * nw[tid];
    float n1 = v1 * rms * nw[tid + 256];
    float n2 = v2 * rms * nw[tid + 512];
    float n3 = v3 * rms * nw[tid + 768];

    float2 c0 = tab[s * D2 + tid];
    float2 c1 = tab[s * D2 + tid + 256];
    float h0 = n0 * c0.x - n2 * c0.y;
    float h2 = n0 * c0.y + n2 * c0.x;
    float h1 = n1 * c1.x - n3 * c1.y;
    float h3 = n1 * c1.y + n3 * c1.x;

    size_t base = (size_t)t * Dm;
    hid[base + tid]       = f2bf(h0);
    hid[base + tid + 256] = f2bf(h1);
    hid[base + tid + 512] = f2bf(h2);
    hid[base + tid + 768] = f2bf(h3);

    float p[8];
    #pragma unroll
    for (int e = 0; e < 8; e++) {
        const float* r = rW + (size_t)e * Dm;
        p[e] = h0 * r[tid] + h1 * r[tid + 256] + h2 * r[tid + 512] + h3 * r[tid + 768];
    }
    #pragma unroll
    for (int e = 0; e < 8; e++)
        #pragma unroll
        for (int o = 32; o; o >>= 1) p[e] += __shfl_down(p[e], o);
    __shared__ float rl[4][8];
    if (lane == 0) {
        #pragma unroll
        for (int e = 0; e < 8; e++) rl[wid][e] = p[e];
    }
    __syncthreads();
    if (tid == 0) {
        float lg[8];
        #pragma unroll
        for (int e = 0; e < 8; e++) lg[e] = rl[0][e] + rl[1][e] + rl[2][e] + rl[3][e];
        float m = lg[0];
        #pragma unroll
        for (int e = 1; e < 8; e++) m = fmaxf(m, lg[e]);
        int i0 = 0; float b0 = lg[0];
        #pragma unroll
        for (int e = 1; e < 8; e++) if (lg[e] > b0) { b0 = lg[e]; i0 = e; }
        int i1 = -1; float b1 = -3.0e38f;
        #pragma unroll
        for (int e = 0; e < 8; e++) if (e != i0 && lg[e] > b1) { b1 = lg[e]; i1 = e; }
        float p0 = expf(b0 - m), p1 = expf(b1 - m);
        float inv = 1.0f / (p0 + p1);
        t2i[2 * t] = i0; t2i[2 * t + 1] = i1;
        t2g[2 * t] = p0 * inv; t2g[2 * t + 1] = p1 * inv;
        atomicAdd(&meta[i0], 1);
        atomicAdd(&meta[i1], 1);
    }
}

// ---------------- prefix offsets (padded to PADU=128) ----------------
__global__ void k_offsets(int* meta) {
    if (threadIdx.x == 0 && blockIdx.x == 0) {
        int acc = 0;
        for (int e = 0; e < 8; e++) {
            meta[8 + e] = acc;
            acc += ((meta[e] + PADU - 1) / PADU) * PADU;
        }
        meta[16] = acc;                       // padded_total
        for (int e = 0; e < 8; e++) meta[17 + e] = meta[8 + e]; // cursors
    }
}

// ---------------- slot placement ----------------
__global__ void k_place(const int* __restrict__ t2i, const float* __restrict__ t2g,
                        int* __restrict__ slot_token, float* __restrict__ slot_gate,
                        int* __restrict__ t2s, int* __restrict__ meta) {
    int t = blockIdx.x * 256 + threadIdx.x;
    if (t >= TOKENS) return;
    #pragma unroll
    for (int k = 0; k < 2; k++) {
        int e = t2i[2 * t + k];
        int pos = atomicAdd(&meta[17 + e], 1);
        slot_token[pos] = t;
        slot_gate[pos]  = t2g[2 * t + k];
        t2s[2 * t + k]  = pos;
    }
}

// ---------------- GEMM1: act = silu(hid@w1^T) * (hid@w3^T) ----------------
// 128 rows x 64 H-cols per block; dual-B (w1 rows 0-63 of Bs, w3 rows 64-127)
__global__ __launch_bounds__(256) void k_gemm1(
    const unsigned short* __restrict__ hid,
    const unsigned short* __restrict__ w1b, const unsigned short* __restrict__ w3b,
    const int* __restrict__ slot_token, unsigned short* __restrict__ act,
    const int* __restrict__ meta)
{
    int row0 = blockIdx.y * 128;
    if (row0 >= meta[16]) return;
    int e = 0;
    #pragma unroll
    for (int q = 1; q < 8; q++) if (row0 >= meta[8 + q]) e = q;
    int h0 = blockIdx.x * 64;

    __shared__ unsigned short As[128 * 32];
    __shared__ unsigned short Bs[128 * 32];

    int tid = threadIdx.x, lane = tid & 63, w = tid >> 6;
    int wm = w >> 1, wn = w & 1;
    int frow = lane & 15, fk = (lane >> 4) * 8;
    int srow = tid >> 2, seg = tid & 3;     // staging: row 0..63, 8-elem segment

    int tA0 = slot_token[row0 + srow];       if (tA0 < 0) tA0 = 0;
    int tA1 = slot_token[row0 + 64 + srow];  if (tA1 < 0) tA1 = 0;
    const unsigned short* srcA0 = hid + (size_t)tA0 * Dm + seg * 8;
    const unsigned short* srcA1 = hid + (size_t)tA1 * Dm + seg * 8;
    const unsigned short* srcB1 = w1b + ((size_t)e * Hm + h0 + srow) * Dm + seg * 8;
    const unsigned short* srcB3 = w3b + ((size_t)e * Hm + h0 + srow) * Dm + seg * 8;
    unsigned short* ldsA0 = &As[tid * 8];
    unsigned short* ldsA1 = &As[2048 + tid * 8];
    unsigned short* ldsB1 = &Bs[tid * 8];
    unsigned short* ldsB3 = &Bs[2048 + tid * 8];

    f32x4 accG[4][2] = {};
    f32x4 accU[4][2] = {};

    for (int k0 = 0; k0 < Dm; k0 += 32) {
        gld16(srcA0 + k0, ldsA0);
        gld16(srcA1 + k0, ldsA1);
        gld16(srcB1 + k0, ldsB1);
        gld16(srcB3 + k0, ldsB3);
        __syncthreads();

        s16x8 am[4], bg[2], bu[2];
        #pragma unroll
        for (int i = 0; i < 4; i++)
            am[i] = *(const s16x8*)&As[(wm * 64 + i * 16 + frow) * 32 + fk];
        #pragma unroll
        for (int j = 0; j < 2; j++) {
            bg[j] = *(const s16x8*)&Bs[(wn * 32 + j * 16 + frow) * 32 + fk];
            bu[j] = *(const s16x8*)&Bs[(64 + wn * 32 + j * 16 + frow) * 32 + fk];
        }
        #pragma unroll
        for (int i = 0; i < 4; i++)
            #pragma unroll
            for (int j = 0; j < 2; j++) {
                accG[i][j] = mfma16(am[i], bg[j], accG[i][j]);
                accU[i][j] = mfma16(am[i], bu[j], accU[i][j]);
            }
        __syncthreads();
    }

    #pragma unroll
    for (int i = 0; i < 4; i++)
        #pragma unroll
        for (int j = 0; j < 2; j++)
            #pragma unroll
            for (int r = 0; r < 4; r++) {
                int sr = row0 + wm * 64 + i * 16 + (lane >> 4) * 4 + r;
                int hc = h0 + wn * 32 + j * 16 + (lane & 15);
                float g = accG[i][j][r], u = accU[i][j][r];
                float a = g / (1.0f + expf(-g)) * u;
                act[(size_t)sr * Hm + hc] = f2bf(a);
            }
}

// ---------------- GEMM2: sout[slot] = gate * (act @ w2^T), bf16 ----------------
// 128 rows x 128 D-cols per block
__global__ __launch_bounds__(256) void k_gemm2(
    const unsigned short* __restrict__ act, const unsigned short* __restrict__ w2b,
    const float* __restrict__ slot_gate,
    unsigned short* __restrict__ sout, const int* __restrict__ meta)
{
    int row0 = blockIdx.y * 128;
    if (row0 >= meta[16]) return;
    int e = 0;
    #pragma unroll
    for (int q = 1; q < 8; q++) if (row0 >= meta[8 + q]) e = q;
    int d0 = blockIdx.x * 128;

    __shared__ unsigned short As[128 * 32];
    __shared__ unsigned short Bs[128 * 32];
    __shared__ float sgat[128];

    int tid = threadIdx.x, lane = tid & 63, w = tid >> 6;
    int wm = w >> 1, wn = w & 1;
    int frow = lane & 15, fk = (lane >> 4) * 8;
    int srow = tid >> 2, seg = tid & 3;

    if (tid < 128) sgat[tid] = slot_gate[row0 + tid];

    const unsigned short* srcA0 = act + (size_t)(row0 + srow) * Hm + seg * 8;
    const unsigned short* srcA1 = act + (size_t)(row0 + 64 + srow) * Hm + seg * 8;
    const unsigned short* srcB0 = w2b + ((size_t)e * Dm + d0 + srow) * Hm + seg * 8;
    const unsigned short* srcB1 = w2b + ((size_t)e * Dm + d0 + 64 + srow) * Hm + seg * 8;
    unsigned short* ldsA0 = &As[tid * 8];
    unsigned short* ldsA1 = &As[2048 + tid * 8];
    unsigned short* ldsB0 = &Bs[tid * 8];
    unsigned short* ldsB1 = &Bs[2048 + tid * 8];

    f32x4 acc[4][4] = {};

    for (int k0 = 0; k0 < Hm; k0 += 32) {
        gld16(srcA0 + k0, ldsA0);
        gld16(srcA1 + k0, ldsA1);
        gld16(srcB0 + k0, ldsB0);
        gld16(srcB1 + k0, ldsB1);
        __syncthreads();

        s16x8 am[4], bn[4];
        #pragma unroll
        for (int i = 0; i < 4; i++)
            am[i] = *(const s16x8*)&As[(wm * 64 + i * 16 + frow) * 32 + fk];
        #pragma unroll
        for (int j = 0; j < 4; j++)
            bn[j] = *(const s16x8*)&Bs[(wn * 64 + j * 16 + frow) * 32 + fk];
        #pragma unroll
        for (int i = 0; i < 4; i++)
            #pragma unroll
            for (int j = 0; j < 4; j++)
                acc[i][j] = mfma16(am[i], bn[j], acc[i][j]);
        __syncthreads();
    }

    #pragma unroll
    for (int i = 0; i < 4; i++) {
        #pragma unroll
        for (int r = 0; r < 4; r++) {
            int srl = wm * 64 + i * 16 + (lane >> 4) * 4 + r;
            float gate = sgat[srl];
            size_t rb = (size_t)(row0 + srl) * Dm;
            #pragma unroll
            for (int j = 0; j < 4; j++) {
                int dc = d0 + wn * 64 + j * 16 + (lane & 15);
                sout[rb + dc] = f2bf(gate * acc[i][j][r]);
            }
        }
    }
}

// ---------------- final gather: out = x + sout[s0] + sout[s1] ----------------
__global__ __launch_bounds__(256) void k_final(
    const float* __restrict__ x, const unsigned short* __restrict__ sout,
    const int* __restrict__ t2s, float* __restrict__ out)
{
    int t = blockIdx.x;
    int tid = threadIdx.x;
    int s0 = t2s[2 * t], s1 = t2s[2 * t + 1];
    const float4*  xr = (const float4*)(x + (size_t)t * Dm);
    const ushort4* a  = (const ushort4*)(sout + (size_t)s0 * Dm);
    const ushort4* b  = (const ushort4*)(sout + (size_t)s1 * Dm);
    float4* o = (float4*)(out + (size_t)t * Dm);
    float4 xv = xr[tid];
    ushort4 av = a[tid], bv = b[tid];
    float4 r;
    r.x = xv.x + bf2f(av.x) + bf2f(bv.x);
    r.y = xv.y + bf2f(av.y) + bf2f(bv.y);
    r.z = xv.z + bf2f(av.z) + bf2f(bv.z);
    r.w = xv.w + bf2f(av.w) + bf2f(bv.w);
    o[tid] = r;
}

extern "C" void kernel_launch(void* const* d_in, const int* in_sizes, int n_in,
                              void* d_out, int out_size, void* d_ws, size_t ws_size,
                              hipStream_t stream) {
    const float* x  = (const float*)d_in[0];
    const float* nw = (const float*)d_in[1];
    const float* rW = (const float*)d_in[2];
    const float* w1 = (const float*)d_in[3];
    const float* w3 = (const float*)d_in[4];
    const float* w2 = (const float*)d_in[5];
    float* out = (float*)d_out;
    char* ws = (char*)d_ws;

    float2* tab = (float2*)(ws + OF_TAB);
    unsigned short* hid = (unsigned short*)(ws + OF_HID);
    unsigned short* act = (unsigned short*)(ws + OF_ACT);
    unsigned short* w1b = (unsigned short*)(ws + OF_W1B);
    unsigned short* w3b = (unsigned short*)(ws + OF_W3B);
    unsigned short* w2b = (unsigned short*)(ws + OF_W2B);
    int*   t2i  = (int*)(ws + OF_T2I);
    float* t2g  = (float*)(ws + OF_T2G);
    int*   t2s  = (int*)(ws + OF_T2S);
    int*   stok = (int*)(ws + OF_ST);
    float* sgat = (float*)(ws + OF_SG);
    int*   meta = (int*)(ws + OF_MT);
    unsigned short* sout = (unsigned short*)(ws + OF_SO);

    k_init<<<(SLOTPAD + 255) / 256, 256, 0, stream>>>(stok, meta);
    k_table<<<(Sm * D2) / 256, 256, 0, stream>>>(tab);
    k_convert<<<NWE / (256 * 8), 256, 0, stream>>>(w1, w1b);
    k_convert<<<NWE / (256 * 8), 256, 0, stream>>>(w3, w3b);
    k_convert<<<NWE / (256 * 8), 256, 0, stream>>>(w2, w2b);
    k_token<<<TOKENS, 256, 0, stream>>>(x, nw, rW, tab, hid, t2i, t2g, meta);
    k_offsets<<<1, 64, 0, stream>>>(meta);
    k_place<<<TOKENS / 256, 256, 0, stream>>>(t2i, t2g, stok, sgat, t2s, meta);

    dim3 g1(Hm / 64, SLOTPAD / 128);
    k_gemm1<<<g1, 256, 0, stream>>>(hid, w1b, w3b, stok, act, meta);
    dim3 g2(Dm / 128, SLOTPAD / 128);
    k_gemm2<<<g2, 256, 0, stream>>>(act, w2b, sgat, sout, meta);
    k_final<<<TOKENS, 256, 0, stream>>>(x, sout, t2s, out);
}